// Round 3
// baseline (1545.222 us; speedup 1.0000x reference)
//
#include <hip/hip_runtime.h>

#define H 128
#define NPB 128       // nodes per bucket (= gather LDS tile height)
#define NB_MAX 1024   // max buckets -> n_nodes <= 131072
#define FILL_CH 4096  // edges per bucket_fill block

// fp32 -> bf16 round-to-nearest-even
static __device__ __forceinline__ unsigned short f2bf(float f) {
  unsigned u = __float_as_uint(f);
  u += 0x7FFFu + ((u >> 16) & 1u);
  return (unsigned short)(u >> 16);
}

// ---------------------------------------------------------------------------
// GEMM: X0 = notes @ w, register-blocked (R4-proven, verbatim).
// x0 stored bf16; rows >= garment written fp32 to output tail.
// ---------------------------------------------------------------------------
__global__ __launch_bounds__(256) void gemm_kernel(
    const float* __restrict__ notes, const float* __restrict__ w,
    const int* __restrict__ g_ptr, unsigned short* __restrict__ x0h,
    float* __restrict__ out, int n_nodes) {
  __shared__ float wtile[32 * H];   // 16 KB
  __shared__ float ntile[64 * 32];  // 8 KB
  const int tid = threadIdx.x;
  const int tx = tid & 31;
  const int ty = tid >> 5;
  const int rowBlk = blockIdx.x * 64;
  const int g = *g_ptr;

  float acc[8][4];
#pragma unroll
  for (int i = 0; i < 8; ++i)
#pragma unroll
    for (int j = 0; j < 4; ++j) acc[i][j] = 0.f;

  for (int kc = 0; kc < H; kc += 32) {
    __syncthreads();
    {
      const float4* wg = (const float4*)(w + (size_t)kc * H);
      float4* wl = (float4*)wtile;
#pragma unroll
      for (int i = 0; i < 4; ++i) wl[tid + i * 256] = wg[tid + i * 256];
    }
    {
      float4* nl = (float4*)ntile;
#pragma unroll
      for (int i = 0; i < 2; ++i) {
        const int idx = tid + i * 256;
        const int row = idx >> 3;
        const int q = idx & 7;
        const int rr = min(rowBlk + row, n_nodes - 1);
        nl[idx] = *(const float4*)(notes + (size_t)rr * H + kc + q * 4);
      }
    }
    __syncthreads();
#pragma unroll 8
    for (int kk = 0; kk < 32; ++kk) {
      const float4 b4 = *(const float4*)&wtile[kk * H + tx * 4];
      float a[8];
#pragma unroll
      for (int i = 0; i < 8; ++i) a[i] = ntile[(ty * 8 + i) * 32 + kk];
#pragma unroll
      for (int i = 0; i < 8; ++i) {
        acc[i][0] += a[i] * b4.x;
        acc[i][1] += a[i] * b4.y;
        acc[i][2] += a[i] * b4.z;
        acc[i][3] += a[i] * b4.w;
      }
    }
  }

#pragma unroll
  for (int i = 0; i < 8; ++i) {
    const int r = rowBlk + ty * 8 + i;
    if (r < n_nodes) {
      ushort4 h;
      h.x = f2bf(acc[i][0]);
      h.y = f2bf(acc[i][1]);
      h.z = f2bf(acc[i][2]);
      h.w = f2bf(acc[i][3]);
      *(ushort4*)(x0h + (size_t)r * H + tx * 4) = h;
      if (r >= g) {
        float4 v;
        v.x = acc[i][0]; v.y = acc[i][1]; v.z = acc[i][2]; v.w = acc[i][3];
        *(float4*)(out + (size_t)(n_nodes + r - g) * H + tx * 4) = v;
      }
    }
  }
}

// ---------------------------------------------------------------------------
// Bucket count: LDS histogram of src>>7, coalesced fire-and-forget flush.
// ---------------------------------------------------------------------------
__global__ __launch_bounds__(256) void bucket_count_kernel(
    const int* __restrict__ esrc, int* __restrict__ bucketCount, int n_edges,
    int nb) {
  __shared__ int cnt[NB_MAX];
  for (int i = threadIdx.x; i < nb; i += 256) cnt[i] = 0;
  __syncthreads();
  int i = blockIdx.x * 256 + threadIdx.x;
  const int stride = gridDim.x * 256;
  for (; i < n_edges; i += stride) atomicAdd(&cnt[esrc[i] >> 7], 1);
  __syncthreads();
  for (int j = threadIdx.x; j < nb; j += 256) {
    const int c = cnt[j];
    if (c) atomicAdd(&bucketCount[j], c);
  }
}

// ---------------------------------------------------------------------------
// Bucket scan: single block; exclusive prefix -> bucketBase (nb+1), cursor.
// ---------------------------------------------------------------------------
__global__ __launch_bounds__(256) void bucket_scan_kernel(
    const int* __restrict__ bucketCount, int* __restrict__ bucketBase,
    int* __restrict__ bucketCursor, int nb) {
  __shared__ int part[256];
  const int t = threadIdx.x;
  const int K = (nb + 255) / 256;
  const int lo = t * K;
  const int hi = min(lo + K, nb);
  int sum = 0;
  for (int i = lo; i < hi; ++i) sum += bucketCount[i];
  part[t] = sum;
  __syncthreads();
  for (int o = 1; o < 256; o <<= 1) {
    const int tv = (t >= o) ? part[t - o] : 0;
    __syncthreads();
    part[t] += tv;
    __syncthreads();
  }
  int run = (t == 0) ? 0 : part[t - 1];
  for (int i = lo; i < hi; ++i) {
    bucketBase[i] = run;
    bucketCursor[i] = run;
    run += bucketCount[i];
  }
  if (t == 255) bucketBase[nb] = part[255];
}

// ---------------------------------------------------------------------------
// Bucket fill (R0-proven structure, NPB=128): per-block LDS count -> scan ->
// one coalesced RT atomic per (block,bucket) -> LDS-staged grouping ->
// contiguous-run global flush. sedge entry: {dst, weight-bits}; srcloc:
// src & 127.
// ---------------------------------------------------------------------------
__global__ __launch_bounds__(256) void bucket_fill_kernel(
    const int* __restrict__ esrc, const int* __restrict__ edst,
    const float* __restrict__ ew, int* __restrict__ bucketCursor,
    int2* __restrict__ sedge, unsigned char* __restrict__ srcloc, int n_edges,
    int nb) {
  __shared__ int2 stage[FILL_CH];            // 32 KB
  __shared__ unsigned short bkt16[FILL_CH];  // 8 KB
  __shared__ unsigned char loc8[FILL_CH];    // 4 KB
  __shared__ int cntA[NB_MAX];               // 4 KB (becomes gbase)
  __shared__ int lbase[NB_MAX];              // 4 KB
  __shared__ int cntC[NB_MAX];               // 4 KB
  const int t = threadIdx.x;
  const int base = blockIdx.x * FILL_CH;
  const int edgesInBlock = min(FILL_CH, n_edges - base);

  for (int i = t; i < nb; i += 256) {
    cntA[i] = 0;
    cntC[i] = 0;
  }
  __syncthreads();

  // Phase A: count.
  for (int k = 0; k < FILL_CH / 256; ++k) {
    const int e = base + k * 256 + t;
    if (e < n_edges) atomicAdd(&cntA[esrc[e] >> 7], 1);
  }
  __syncthreads();

  // Phase B: exclusive scan of cntA -> lbase.
  {
    __shared__ int part[256];
    const int K = (nb + 255) / 256;
    const int lo = t * K;
    const int hi = min(lo + K, nb);
    int sum = 0;
    for (int i = lo; i < hi; ++i) sum += cntA[i];
    part[t] = sum;
    __syncthreads();
    for (int o = 1; o < 256; o <<= 1) {
      const int tv = (t >= o) ? part[t - o] : 0;
      __syncthreads();
      part[t] += tv;
      __syncthreads();
    }
    int run = (t == 0) ? 0 : part[t - 1];
    for (int i = lo; i < hi; ++i) {
      lbase[i] = run;
      run += cntA[i];
    }
  }
  __syncthreads();
  // One RT atomic per nonempty bucket; repurpose cntA as gbase.
  for (int i = t; i < nb; i += 256) {
    const int c = cntA[i];
    cntA[i] = c ? atomicAdd(&bucketCursor[i], c) : 0;
  }
  __syncthreads();

  // Phase C: re-read edges, rank within bucket, stage grouped in LDS.
  for (int k = 0; k < FILL_CH / 256; ++k) {
    const int e = base + k * 256 + t;
    if (e < n_edges) {
      const int s = esrc[e];
      const int b = s >> 7;
      const int r = atomicAdd(&cntC[b], 1);
      const int sp = lbase[b] + r;
      int2 pk;
      pk.x = edst[e];
      pk.y = __float_as_int(ew[e]);
      stage[sp] = pk;
      bkt16[sp] = (unsigned short)b;
      loc8[sp] = (unsigned char)(s & 127);
    }
  }
  __syncthreads();

  // Phase D: flush contiguous runs.
  for (int j = t; j < edgesInBlock; j += 256) {
    const int b = bkt16[j];
    const int pos = cntA[b] + (j - lbase[b]);
    sedge[pos] = stage[j];
    srcloc[pos] = loc8[j];
  }
}

// ---------------------------------------------------------------------------
// Gather v3: one block per 128-node bucket; fp32 accumulator tile in LDS
// (split lo/hi arrays -> ds_add_f32 at bank=lane%32, 2-way = free).
// Edge-parallel with 16 independent row loads in flight per wave -> breaks
// the per-node serial dependent-load chain (v1 was latency-bound at 39%
// VALUBusy). No node-grouping needed -> bucket_sort deleted.
// ---------------------------------------------------------------------------
__global__ __launch_bounds__(256) void gather_lds_kernel(
    const int* __restrict__ bucketBase, const int2* __restrict__ sedge,
    const unsigned char* __restrict__ srcloc,
    const unsigned short* __restrict__ x0h, const float* __restrict__ b,
    float* __restrict__ out, int n_nodes) {
  __shared__ float accLo[NPB * 64];  // 32 KB: [loc][lane] -> dim 2*lane
  __shared__ float accHi[NPB * 64];  // 32 KB: [loc][lane] -> dim 2*lane+1
  const int t = threadIdx.x;
  const int lane = t & 63;
  const int wv = t >> 6;  // wave 0..3
  const int bucket = blockIdx.x;
  const int nodeBase = bucket * NPB;

  {
    float4* zl = (float4*)accLo;
    float4* zh = (float4*)accHi;
    const float4 z4 = make_float4(0.f, 0.f, 0.f, 0.f);
    for (int i = t; i < NPB * 16; i += 256) {
      zl[i] = z4;
      zh[i] = z4;
    }
  }
  __syncthreads();

  const int beg = bucketBase[bucket];
  const int end = bucketBase[bucket + 1];
  const int cnt = end - beg;
  const unsigned* __restrict__ x0u = (const unsigned*)x0h;

  // Each wave owns chunks of 16 edges, strided by 64 across the 4 waves.
  for (int base = wv * 16; base < cnt; base += 64) {
    int d[16];
    float we[16];
    int lc[16];
#pragma unroll
    for (int j = 0; j < 16; ++j) {
      const int ei = base + j;
      const int ec = min(ei, cnt - 1);        // clamp tail; weight zeroed
      const int2 m = sedge[beg + ec];
      d[j] = m.x;
      we[j] = (ei < cnt) ? __int_as_float(m.y) : 0.f;
      lc[j] = srcloc[beg + ec];
    }
    unsigned u[16];
#pragma unroll
    for (int j = 0; j < 16; ++j) u[j] = x0u[(size_t)d[j] * 64 + lane];
#pragma unroll
    for (int j = 0; j < 16; ++j) {
      atomicAdd(&accLo[lc[j] * 64 + lane], __uint_as_float(u[j] << 16) * we[j]);
      atomicAdd(&accHi[lc[j] * 64 + lane],
                __uint_as_float(u[j] & 0xFFFF0000u) * we[j]);
    }
  }
  __syncthreads();

  // Epilogue: bias + relu, coalesced float2 rows.
  const float2 bb = ((const float2*)b)[lane];
  for (int n = wv; n < NPB; n += 4) {
    const int node = nodeBase + n;
    if (node < n_nodes) {
      float2 r;
      r.x = fmaxf(accLo[n * 64 + lane] + bb.x, 0.f);
      r.y = fmaxf(accHi[n * 64 + lane] + bb.y, 0.f);
      ((float2*)out)[(size_t)node * 64 + lane] = r;
    }
  }
}

// ---------------------------------------------------------------------------
// Fallback path (constraints violated): atomic scatter + epilogue.
// ---------------------------------------------------------------------------
__global__ __launch_bounds__(256) void scatter_kernel(
    const int* __restrict__ esrc, const int* __restrict__ edst,
    const float* __restrict__ ew, const unsigned short* __restrict__ x0h,
    float* __restrict__ acc, int n_edges) {
  const int lane = threadIdx.x & 63;
  const int waveId = blockIdx.x * (blockDim.x >> 6) + (threadIdx.x >> 6);
  const int nWaves = gridDim.x * (blockDim.x >> 6);
  const unsigned* __restrict__ x0u = (const unsigned*)x0h;
  for (int e = waveId; e < n_edges; e += nWaves) {
    const int s = esrc[e];
    const int d = edst[e];
    const float wt = ew[e];
    const unsigned u = x0u[(size_t)d * 64 + lane];
    float* p = acc + (size_t)s * H + lane * 2;
    atomicAdd(p, __uint_as_float(u << 16) * wt);
    atomicAdd(p + 1, __uint_as_float(u & 0xFFFF0000u) * wt);
  }
}

__global__ __launch_bounds__(256) void epilogue_kernel(
    float* __restrict__ out, const float* __restrict__ b, int n4) {
  const int i = blockIdx.x * blockDim.x + threadIdx.x;
  if (i >= n4) return;
  float4* o4 = (float4*)out;
  const float4* b4 = (const float4*)b;
  float4 v = o4[i];
  const float4 bb = b4[i & 31];
  v.x = fmaxf(v.x + bb.x, 0.f);
  v.y = fmaxf(v.y + bb.y, 0.f);
  v.z = fmaxf(v.z + bb.z, 0.f);
  v.w = fmaxf(v.w + bb.w, 0.f);
  o4[i] = v;
}

extern "C" void kernel_launch(void* const* d_in, const int* in_sizes, int n_in,
                              void* d_out, int out_size, void* d_ws, size_t ws_size,
                              hipStream_t stream) {
  const float* notes = (const float*)d_in[0];
  const float* w     = (const float*)d_in[1];
  const float* b     = (const float*)d_in[2];
  const int*   esrc  = (const int*)d_in[3];
  const int*   edst  = (const int*)d_in[4];
  const float* ew    = (const float*)d_in[5];
  const int*   gptr  = (const int*)d_in[6];

  const int n_nodes = in_sizes[0] / H;
  const int n_edges = in_sizes[3];
  float* out = (float*)d_out;

  const int nb = (n_nodes + NPB - 1) / NPB;

  // Workspace carve-up (256B-aligned regions).
  char* ws = (char*)d_ws;
  size_t p = 0;
  auto alloc = [&](size_t bytes) -> char* {
    char* cur = ws + p;
    p = (p + bytes + 255) & ~(size_t)255;
    return cur;
  };
  unsigned short* x0h = (unsigned short*)alloc((size_t)n_nodes * H * 2);
  int*  bucketCount  = (int*)alloc((size_t)nb * sizeof(int));
  int*  bucketBase   = (int*)alloc(((size_t)nb + 1) * sizeof(int));
  int*  bucketCursor = (int*)alloc((size_t)nb * sizeof(int));
  int2* sedge        = (int2*)alloc((size_t)n_edges * sizeof(int2));
  unsigned char* srcloc = (unsigned char*)alloc((size_t)n_edges);
  const bool ok = (p <= ws_size) && (nb <= NB_MAX);

  // GEMM (also writes concat tail rows fp32; x0 stored bf16).
  gemm_kernel<<<(n_nodes + 63) / 64, 256, 0, stream>>>(notes, w, gptr, x0h, out,
                                                       n_nodes);

  if (ok) {
    hipMemsetAsync(bucketCount, 0, (size_t)nb * sizeof(int), stream);
    bucket_count_kernel<<<256, 256, 0, stream>>>(esrc, bucketCount, n_edges,
                                                 nb);
    bucket_scan_kernel<<<1, 256, 0, stream>>>(bucketCount, bucketBase,
                                              bucketCursor, nb);
    bucket_fill_kernel<<<(n_edges + FILL_CH - 1) / FILL_CH, 256, 0, stream>>>(
        esrc, edst, ew, bucketCursor, sedge, srcloc, n_edges, nb);
    gather_lds_kernel<<<nb, 256, 0, stream>>>(bucketBase, sedge, srcloc, x0h,
                                              b, out, n_nodes);
  } else {
    hipMemsetAsync(d_out, 0, (size_t)n_nodes * H * sizeof(float), stream);
    scatter_kernel<<<2048, 256, 0, stream>>>(esrc, edst, ew, x0h, out, n_edges);
    const int n4 = n_nodes * H / 4;
    epilogue_kernel<<<(n4 + 255) / 256, 256, 0, stream>>>(out, b, n4);
  }
}

// Round 4
// 323.852 us; speedup vs baseline: 4.7714x; 4.7714x over previous
//
#include <hip/hip_runtime.h>

#define H 128
#define NPB 256       // nodes per coarse bucket
#define NB_MAX 1024   // max buckets (LDS arrays) -> n_nodes <= 262144
#define FILL_CH 4096  // edges per bucket_fill block

// fp32 -> bf16 round-to-nearest-even
static __device__ __forceinline__ unsigned short f2bf(float f) {
  unsigned u = __float_as_uint(f);
  u += 0x7FFFu + ((u >> 16) & 1u);
  return (unsigned short)(u >> 16);
}

// ---------------------------------------------------------------------------
// GEMM: X0 = notes @ w, register-blocked (R4-proven, verbatim), plus
// block 0 zeroes bucketCount (replaces a hipMemsetAsync dispatch).
// ---------------------------------------------------------------------------
__global__ __launch_bounds__(256) void gemm_kernel(
    const float* __restrict__ notes, const float* __restrict__ w,
    const int* __restrict__ g_ptr, unsigned short* __restrict__ x0h,
    float* __restrict__ out, int* __restrict__ bucketCount, int nb,
    int n_nodes) {
  __shared__ float wtile[32 * H];   // 16 KB
  __shared__ float ntile[64 * 32];  // 8 KB
  const int tid = threadIdx.x;
  const int tx = tid & 31;
  const int ty = tid >> 5;
  const int rowBlk = blockIdx.x * 64;
  const int g = *g_ptr;

  if (blockIdx.x == 0) {
    for (int i = tid; i < nb; i += 256) bucketCount[i] = 0;
  }

  float acc[8][4];
#pragma unroll
  for (int i = 0; i < 8; ++i)
#pragma unroll
    for (int j = 0; j < 4; ++j) acc[i][j] = 0.f;

  for (int kc = 0; kc < H; kc += 32) {
    __syncthreads();
    {
      const float4* wg = (const float4*)(w + (size_t)kc * H);
      float4* wl = (float4*)wtile;
#pragma unroll
      for (int i = 0; i < 4; ++i) wl[tid + i * 256] = wg[tid + i * 256];
    }
    {
      float4* nl = (float4*)ntile;
#pragma unroll
      for (int i = 0; i < 2; ++i) {
        const int idx = tid + i * 256;
        const int row = idx >> 3;
        const int q = idx & 7;
        const int rr = min(rowBlk + row, n_nodes - 1);
        nl[idx] = *(const float4*)(notes + (size_t)rr * H + kc + q * 4);
      }
    }
    __syncthreads();
#pragma unroll 8
    for (int kk = 0; kk < 32; ++kk) {
      const float4 b4 = *(const float4*)&wtile[kk * H + tx * 4];
      float a[8];
#pragma unroll
      for (int i = 0; i < 8; ++i) a[i] = ntile[(ty * 8 + i) * 32 + kk];
#pragma unroll
      for (int i = 0; i < 8; ++i) {
        acc[i][0] += a[i] * b4.x;
        acc[i][1] += a[i] * b4.y;
        acc[i][2] += a[i] * b4.z;
        acc[i][3] += a[i] * b4.w;
      }
    }
  }

#pragma unroll
  for (int i = 0; i < 8; ++i) {
    const int r = rowBlk + ty * 8 + i;
    if (r < n_nodes) {
      ushort4 h;
      h.x = f2bf(acc[i][0]);
      h.y = f2bf(acc[i][1]);
      h.z = f2bf(acc[i][2]);
      h.w = f2bf(acc[i][3]);
      *(ushort4*)(x0h + (size_t)r * H + tx * 4) = h;
      if (r >= g) {
        float4 v;
        v.x = acc[i][0]; v.y = acc[i][1]; v.z = acc[i][2]; v.w = acc[i][3];
        *(float4*)(out + (size_t)(n_nodes + r - g) * H + tx * 4) = v;
      }
    }
  }
}

// ---------------------------------------------------------------------------
// Bucket count: LDS histogram of src>>8 (int atomics), coalesced flush.
// ---------------------------------------------------------------------------
__global__ __launch_bounds__(256) void bucket_count_kernel(
    const int* __restrict__ esrc, int* __restrict__ bucketCount, int n_edges,
    int nb) {
  __shared__ int cnt[NB_MAX];
  for (int i = threadIdx.x; i < nb; i += 256) cnt[i] = 0;
  __syncthreads();
  int i = blockIdx.x * 256 + threadIdx.x;
  const int stride = gridDim.x * 256;
  for (; i < n_edges; i += stride) atomicAdd(&cnt[esrc[i] >> 8], 1);
  __syncthreads();
  for (int j = threadIdx.x; j < nb; j += 256) {
    const int c = cnt[j];
    if (c) atomicAdd(&bucketCount[j], c);
  }
}

// ---------------------------------------------------------------------------
// Bucket scan: single block; exclusive prefix -> bucketBase (nb+1), cursor.
// Also writes off[n_nodes] = n_edges.
// ---------------------------------------------------------------------------
__global__ __launch_bounds__(256) void bucket_scan_kernel(
    const int* __restrict__ bucketCount, int* __restrict__ bucketBase,
    int* __restrict__ bucketCursor, int* __restrict__ off, int nb,
    int n_nodes, int n_edges) {
  __shared__ int part[256];
  const int t = threadIdx.x;
  const int K = (nb + 255) / 256;
  const int lo = t * K;
  const int hi = min(lo + K, nb);
  int sum = 0;
  for (int i = lo; i < hi; ++i) sum += bucketCount[i];
  part[t] = sum;
  __syncthreads();
  for (int o = 1; o < 256; o <<= 1) {
    const int tv = (t >= o) ? part[t - o] : 0;
    __syncthreads();
    part[t] += tv;
    __syncthreads();
  }
  int run = (t == 0) ? 0 : part[t - 1];
  for (int i = lo; i < hi; ++i) {
    bucketBase[i] = run;
    bucketCursor[i] = run;
    run += bucketCount[i];
  }
  if (t == 255) {
    bucketBase[nb] = part[255];
    off[n_nodes] = n_edges;
  }
}

// ---------------------------------------------------------------------------
// Bucket fill (R0-proven, verbatim): per-block LDS count -> scan -> one
// coalesced RT atomic per (block,bucket) -> LDS-staged grouping ->
// contiguous-run global flush. Int atomics only.
// ---------------------------------------------------------------------------
__global__ __launch_bounds__(256) void bucket_fill_kernel(
    const int* __restrict__ esrc, const int* __restrict__ edst,
    const float* __restrict__ ew, int* __restrict__ bucketCursor,
    int2* __restrict__ sedge, unsigned char* __restrict__ srcloc, int n_edges,
    int nb) {
  __shared__ int2 stage[FILL_CH];            // 32 KB
  __shared__ unsigned short bkt16[FILL_CH];  // 8 KB
  __shared__ unsigned char loc8[FILL_CH];    // 4 KB
  __shared__ int cntA[NB_MAX];               // 4 KB (becomes gbase)
  __shared__ int lbase[NB_MAX];              // 4 KB
  __shared__ int cntC[NB_MAX];               // 4 KB
  const int t = threadIdx.x;
  const int base = blockIdx.x * FILL_CH;
  const int edgesInBlock = min(FILL_CH, n_edges - base);

  for (int i = t; i < nb; i += 256) {
    cntA[i] = 0;
    cntC[i] = 0;
  }
  __syncthreads();

  // Phase A: count.
  for (int k = 0; k < FILL_CH / 256; ++k) {
    const int e = base + k * 256 + t;
    if (e < n_edges) atomicAdd(&cntA[esrc[e] >> 8], 1);
  }
  __syncthreads();

  // Phase B: exclusive scan of cntA -> lbase.
  {
    __shared__ int part[256];
    const int K = (nb + 255) / 256;
    const int lo = t * K;
    const int hi = min(lo + K, nb);
    int sum = 0;
    for (int i = lo; i < hi; ++i) sum += cntA[i];
    part[t] = sum;
    __syncthreads();
    for (int o = 1; o < 256; o <<= 1) {
      const int tv = (t >= o) ? part[t - o] : 0;
      __syncthreads();
      part[t] += tv;
      __syncthreads();
    }
    int run = (t == 0) ? 0 : part[t - 1];
    for (int i = lo; i < hi; ++i) {
      lbase[i] = run;
      run += cntA[i];
    }
  }
  __syncthreads();
  // One RT atomic per nonempty bucket; repurpose cntA as gbase.
  for (int i = t; i < nb; i += 256) {
    const int c = cntA[i];
    cntA[i] = c ? atomicAdd(&bucketCursor[i], c) : 0;
  }
  __syncthreads();

  // Phase C: re-read edges, rank within bucket, stage grouped in LDS.
  for (int k = 0; k < FILL_CH / 256; ++k) {
    const int e = base + k * 256 + t;
    if (e < n_edges) {
      const int s = esrc[e];
      const int b = s >> 8;
      const int r = atomicAdd(&cntC[b], 1);
      const int sp = lbase[b] + r;
      int2 pk;
      pk.x = edst[e];
      pk.y = __float_as_int(ew[e]);
      stage[sp] = pk;
      bkt16[sp] = (unsigned short)b;
      loc8[sp] = (unsigned char)(s & 255);
    }
  }
  __syncthreads();

  // Phase D: flush contiguous runs.
  for (int j = t; j < edgesInBlock; j += 256) {
    const int b = bkt16[j];
    const int pos = cntA[b] + (j - lbase[b]);
    sedge[pos] = stage[j];
    srcloc[pos] = loc8[j];
  }
}

// ---------------------------------------------------------------------------
// Bucket sort (R0-proven, verbatim): LDS counting sort -> node-ordered
// sedge2 + per-node off[].
// ---------------------------------------------------------------------------
__global__ __launch_bounds__(256) void bucket_sort_kernel(
    const int* __restrict__ bucketBase, const int2* __restrict__ sedge,
    const unsigned char* __restrict__ srcloc, int2* __restrict__ sedge2,
    int* __restrict__ off, int n_nodes) {
  __shared__ int cnt[NPB];      // 1 KB
  __shared__ int nodeOff[NPB];  // 1 KB
  const int t = threadIdx.x;
  const int beg = bucketBase[blockIdx.x];
  const int end = bucketBase[blockIdx.x + 1];
  const int nodeBase = blockIdx.x * NPB;
  const int nodesInBucket = min(NPB, n_nodes - nodeBase);

  cnt[t] = 0;
  __syncthreads();
  for (int j = beg + t; j < end; j += 256) atomicAdd(&cnt[srcloc[j]], 1);
  __syncthreads();
  {
    const int v = cnt[t];
    nodeOff[t] = v;
    __syncthreads();
    for (int o = 1; o < 256; o <<= 1) {
      const int tv = (t >= o) ? nodeOff[t - o] : 0;
      __syncthreads();
      nodeOff[t] += tv;
      __syncthreads();
    }
    nodeOff[t] -= v;  // exclusive
  }
  if (t < nodesInBucket) off[nodeBase + t] = beg + nodeOff[t];
  cnt[t] = 0;
  __syncthreads();
  for (int j = beg + t; j < end; j += 256) {
    const int loc = srcloc[j];
    const int r = atomicAdd(&cnt[loc], 1);
    sedge2[beg + nodeOff[loc] + r] = sedge[j];
  }
}

// ---------------------------------------------------------------------------
// Gather v4: one wave per node, 8-deep batches with next-batch metadata
// prefetch. R1 was latency-bound (VALUBusy 39%): each 4-edge batch exposed
// the full sedge->row dependent chain (~740cy). Here batch k's row loads
// overlap batch k+1's metadata loads, exposing ~one latency per 8 edges.
// ---------------------------------------------------------------------------
__global__ __launch_bounds__(256) void gather_kernel(
    const int* __restrict__ off, const int2* __restrict__ sedge,
    const unsigned short* __restrict__ x0h, const float* __restrict__ b,
    float* __restrict__ out, int n_nodes) {
  const int wave = blockIdx.x * (blockDim.x >> 6) + (threadIdx.x >> 6);
  const int lane = threadIdx.x & 63;
  if (wave >= n_nodes) return;
  const int beg = off[wave];
  const int end = off[wave + 1];
  const unsigned* __restrict__ x0u = (const unsigned*)x0h;

  float2 a[8];
#pragma unroll
  for (int j = 0; j < 8; ++j) a[j] = make_float2(0.f, 0.f);

  if (end > beg) {
    const int last = end - 1;
    int2 m[8];
#pragma unroll
    for (int j = 0; j < 8; ++j) m[j] = sedge[min(beg + j, last)];
    for (int e = beg; e < end; e += 8) {
      // Row loads for current batch (issue first, longest latency).
      unsigned u[8];
#pragma unroll
      for (int j = 0; j < 8; ++j) u[j] = x0u[(size_t)m[j].x * 64 + lane];
      // Prefetch next batch metadata while row loads are in flight.
      int2 mn[8];
      const int e2 = e + 8;
#pragma unroll
      for (int j = 0; j < 8; ++j) mn[j] = sedge[min(e2 + j, last)];
      // FMA (waits only on u).
#pragma unroll
      for (int j = 0; j < 8; ++j) {
        const float wv = (e + j < end) ? __int_as_float(m[j].y) : 0.f;
        a[j].x += __uint_as_float(u[j] << 16) * wv;
        a[j].y += __uint_as_float(u[j] & 0xFFFF0000u) * wv;
      }
#pragma unroll
      for (int j = 0; j < 8; ++j) m[j] = mn[j];
    }
  }

  const float2 bb = ((const float2*)b)[lane];
  float2 r;
  r.x = fmaxf(a[0].x + a[1].x + a[2].x + a[3].x + a[4].x + a[5].x + a[6].x +
                  a[7].x + bb.x,
              0.f);
  r.y = fmaxf(a[0].y + a[1].y + a[2].y + a[3].y + a[4].y + a[5].y + a[6].y +
                  a[7].y + bb.y,
              0.f);
  ((float2*)out)[(size_t)wave * 64 + lane] = r;
}

// ---------------------------------------------------------------------------
// Fallback path (constraints violated): atomic scatter + epilogue.
// (fp32 global atomicAdd = CAS loop under default flags; acceptable only
// as a never-taken safety net.)
// ---------------------------------------------------------------------------
__global__ __launch_bounds__(256) void scatter_kernel(
    const int* __restrict__ esrc, const int* __restrict__ edst,
    const float* __restrict__ ew, const unsigned short* __restrict__ x0h,
    float* __restrict__ acc, int n_edges) {
  const int lane = threadIdx.x & 63;
  const int waveId = blockIdx.x * (blockDim.x >> 6) + (threadIdx.x >> 6);
  const int nWaves = gridDim.x * (blockDim.x >> 6);
  const unsigned* __restrict__ x0u = (const unsigned*)x0h;
  for (int e = waveId; e < n_edges; e += nWaves) {
    const int s = esrc[e];
    const int d = edst[e];
    const float wt = ew[e];
    const unsigned u = x0u[(size_t)d * 64 + lane];
    float* p = acc + (size_t)s * H + lane * 2;
    atomicAdd(p, __uint_as_float(u << 16) * wt);
    atomicAdd(p + 1, __uint_as_float(u & 0xFFFF0000u) * wt);
  }
}

__global__ __launch_bounds__(256) void epilogue_kernel(
    float* __restrict__ out, const float* __restrict__ b, int n4) {
  const int i = blockIdx.x * blockDim.x + threadIdx.x;
  if (i >= n4) return;
  float4* o4 = (float4*)out;
  const float4* b4 = (const float4*)b;
  float4 v = o4[i];
  const float4 bb = b4[i & 31];
  v.x = fmaxf(v.x + bb.x, 0.f);
  v.y = fmaxf(v.y + bb.y, 0.f);
  v.z = fmaxf(v.z + bb.z, 0.f);
  v.w = fmaxf(v.w + bb.w, 0.f);
  o4[i] = v;
}

extern "C" void kernel_launch(void* const* d_in, const int* in_sizes, int n_in,
                              void* d_out, int out_size, void* d_ws, size_t ws_size,
                              hipStream_t stream) {
  const float* notes = (const float*)d_in[0];
  const float* w     = (const float*)d_in[1];
  const float* b     = (const float*)d_in[2];
  const int*   esrc  = (const int*)d_in[3];
  const int*   edst  = (const int*)d_in[4];
  const float* ew    = (const float*)d_in[5];
  const int*   gptr  = (const int*)d_in[6];

  const int n_nodes = in_sizes[0] / H;
  const int n_edges = in_sizes[3];
  float* out = (float*)d_out;

  const int nb = (n_nodes + NPB - 1) / NPB;

  // Workspace carve-up (256B-aligned regions).
  char* ws = (char*)d_ws;
  size_t p = 0;
  auto alloc = [&](size_t bytes) -> char* {
    char* cur = ws + p;
    p = (p + bytes + 255) & ~(size_t)255;
    return cur;
  };
  unsigned short* x0h = (unsigned short*)alloc((size_t)n_nodes * H * 2);
  int*  bucketCount  = (int*)alloc((size_t)nb * sizeof(int));
  int*  bucketBase   = (int*)alloc(((size_t)nb + 1) * sizeof(int));
  int*  bucketCursor = (int*)alloc((size_t)nb * sizeof(int));
  int*  off          = (int*)alloc(((size_t)n_nodes + 1) * sizeof(int));
  int2* sedge        = (int2*)alloc((size_t)n_edges * sizeof(int2));
  int2* sedge2       = (int2*)alloc((size_t)n_edges * sizeof(int2));
  unsigned char* srcloc = (unsigned char*)alloc((size_t)n_edges);
  const bool ok = (p <= ws_size) && (nb <= NB_MAX);

  // GEMM (also writes concat tail rows fp32; zeroes bucketCount in block 0).
  gemm_kernel<<<(n_nodes + 63) / 64, 256, 0, stream>>>(
      notes, w, gptr, x0h, out, bucketCount, ok ? nb : 0, n_nodes);

  if (ok) {
    bucket_count_kernel<<<256, 256, 0, stream>>>(esrc, bucketCount, n_edges,
                                                 nb);
    bucket_scan_kernel<<<1, 256, 0, stream>>>(bucketCount, bucketBase,
                                              bucketCursor, off, nb, n_nodes,
                                              n_edges);
    bucket_fill_kernel<<<(n_edges + FILL_CH - 1) / FILL_CH, 256, 0, stream>>>(
        esrc, edst, ew, bucketCursor, sedge, srcloc, n_edges, nb);
    bucket_sort_kernel<<<nb, 256, 0, stream>>>(bucketBase, sedge, srcloc,
                                               sedge2, off, n_nodes);
    gather_kernel<<<(n_nodes + 3) / 4, 256, 0, stream>>>(off, sedge2, x0h, b,
                                                         out, n_nodes);
  } else {
    hipMemsetAsync(d_out, 0, (size_t)n_nodes * H * sizeof(float), stream);
    scatter_kernel<<<2048, 256, 0, stream>>>(esrc, edst, ew, x0h, out, n_edges);
    const int n4 = n_nodes * H / 4;
    epilogue_kernel<<<(n4 + 255) / 256, 256, 0, stream>>>(out, b, n4);
  }
}